// Round 19
// baseline (610.059 us; speedup 1.0000x reference)
//
#include <hip/hip_runtime.h>
#include <cstdint>
#include <cstddef>

#define DIM 2048
#define NHEADS 16
#define HD 128
#define HIDDEN 8192
#define BSZ 2
#define SEQ 2048
#define MTOT (BSZ*SEQ)   // 4096 rows total

typedef __bf16 bf16_t;
typedef __bf16 bf16x8 __attribute__((ext_vector_type(8)));
typedef __bf16 bf16x4 __attribute__((ext_vector_type(4)));
typedef float  f32x4  __attribute__((ext_vector_type(4)));

// async global->LDS, 16B per lane. LDS dest must be the WAVE-UNIFORM base;
// HW adds lane*16. Global src is per-lane.
__device__ __forceinline__ void gload16(const void* g, void* lds) {
  __builtin_amdgcn_global_load_lds(
      (const __attribute__((address_space(1))) uint32_t*)g,
      (__attribute__((address_space(3))) uint32_t*)lds, 16, 0, 0);
}

// r16 (measured): bare s_barrier + clobber-free waitcnt = -33us vs fully
// pinned. r19: drop the remaining sched_barrier(0) pins too — gload16 and
// s_barrier both carry side effects so their order is already fixed; the pin
// only blocked ds_read/stage interleave inside the phase.
#define SBAR() __builtin_amdgcn_s_barrier()
#define VMW(N) asm volatile("s_waitcnt vmcnt(" #N ")")

// ---------------------------------------------------------------- fused cvt + rmsnorm1
__global__ __launch_bounds__(256)
void cvtrms_k(const float* __restrict__ x, const float* __restrict__ wt,
              bf16_t* __restrict__ xn,
              const float* __restrict__ wq, const float* __restrict__ wk,
              const float* __restrict__ wv, const float* __restrict__ wo,
              const float* __restrict__ w1, const float* __restrict__ w2,
              bf16_t* __restrict__ wdst) {
  const int tid = threadIdx.x;
  if (blockIdx.x < MTOT) {
    const int row = blockIdx.x;
    const float* xr = x + (size_t)row * DIM;
    float4 a = ((const float4*)xr)[tid];
    float4 b = ((const float4*)xr)[tid + 256];
    float ss = a.x*a.x + a.y*a.y + a.z*a.z + a.w*a.w
             + b.x*b.x + b.y*b.y + b.z*b.z + b.w*b.w;
    #pragma unroll
    for (int d = 32; d >= 1; d >>= 1) ss += __shfl_xor(ss, d, 64);
    __shared__ float red[4];
    if ((tid & 63) == 0) red[tid >> 6] = ss;
    __syncthreads();
    float tot = red[0] + red[1] + red[2] + red[3];
    float rs = rsqrtf(tot * (1.0f / DIM) + 1e-6f);
    float4 wa = ((const float4*)wt)[tid];
    float4 wb = ((const float4*)wt)[tid + 256];
    bf16x4 oa = {(__bf16)(a.x*rs*wa.x), (__bf16)(a.y*rs*wa.y),
                 (__bf16)(a.z*rs*wa.z), (__bf16)(a.w*rs*wa.w)};
    bf16x4 ob = {(__bf16)(b.x*rs*wb.x), (__bf16)(b.y*rs*wb.y),
                 (__bf16)(b.z*rs*wb.z), (__bf16)(b.w*rs*wb.w)};
    *(bf16x4*)(xn + (size_t)row*DIM + tid*4)        = oa;
    *(bf16x4*)(xn + (size_t)row*DIM + 1024 + tid*4) = ob;
    return;
  }
  const int S1 = (DIM*DIM) >> 2;
  const int S2 = (DIM*HIDDEN) >> 2;
  const int total = 4*S1 + 2*S2;
  int i = (blockIdx.x - MTOT) * blockDim.x + tid;
  const int stride = (gridDim.x - MTOT) * blockDim.x;
  for (; i < total; i += stride) {
    const float* src; int off;
    if (i < 4*S1) {
      const int r = i >> 20; off = i & (S1 - 1);
      src = (r == 0) ? wq : (r == 1) ? wk : (r == 2) ? wv : wo;
    } else {
      const int j = i - 4*S1;
      if (j < S2) { src = w1; off = j; } else { src = w2; off = j - S2; }
    }
    float4 v = ((const float4*)src)[off];
    bf16x4 o = {(__bf16)v.x, (__bf16)v.y, (__bf16)v.z, (__bf16)v.w};
    ((bf16x4*)wdst)[i] = o;
  }
}

// ---------------------------------------------------------------- RMSNorm (bf16 in -> bf16 out)
__global__ __launch_bounds__(256)
void rmsnorm_bf_k(const bf16_t* __restrict__ h, const float* __restrict__ wt,
                  bf16_t* __restrict__ out) {
  const int row = blockIdx.x;
  const int tid = threadIdx.x;
  bf16x8 v = *(const bf16x8*)(h + (size_t)row*DIM + tid*8);
  float f[8];
  float ss = 0.0f;
  #pragma unroll
  for (int e = 0; e < 8; ++e) { f[e] = (float)v[e]; ss += f[e]*f[e]; }
  #pragma unroll
  for (int d = 32; d >= 1; d >>= 1) ss += __shfl_xor(ss, d, 64);
  __shared__ float red[4];
  if ((tid & 63) == 0) red[tid >> 6] = ss;
  __syncthreads();
  float tot = red[0] + red[1] + red[2] + red[3];
  float rs = rsqrtf(tot * (1.0f / DIM) + 1e-6f);
  float4 wa = ((const float4*)wt)[tid*2];
  float4 wb = ((const float4*)wt)[tid*2 + 1];
  bf16x8 o;
  o[0] = (__bf16)(f[0]*rs*wa.x); o[1] = (__bf16)(f[1]*rs*wa.y);
  o[2] = (__bf16)(f[2]*rs*wa.z); o[3] = (__bf16)(f[3]*rs*wa.w);
  o[4] = (__bf16)(f[4]*rs*wb.x); o[5] = (__bf16)(f[5]*rs*wb.y);
  o[6] = (__bf16)(f[6]*rs*wb.z); o[7] = (__bf16)(f[7]*rs*wb.w);
  *(bf16x8*)(out + (size_t)row*DIM + tid*8) = o;
}

// ---------------------------------------------------------------- 8-phase GEMM helpers (256x256)
template<int MH, int NH>
__device__ __forceinline__ void mm16(f32x4 (&acc)[8][4],
                                     const bf16x8 (&aF)[4][2],
                                     const bf16x8 (&bF)[2][2]) {
  __builtin_amdgcn_s_setprio(1);
  #pragma unroll
  for (int mt = 0; mt < 4; ++mt)
    #pragma unroll
    for (int nt = 0; nt < 2; ++nt)
      #pragma unroll
      for (int kk = 0; kk < 2; ++kk)
        acc[MH*4+mt][NH*2+nt] = __builtin_amdgcn_mfma_f32_16x16x32_bf16(
            aF[mt][kk], bF[nt][kk], acc[MH*4+mt][NH*2+nt], 0, 0, 0);
  __builtin_amdgcn_s_setprio(0);
}

__device__ __forceinline__ void rdA4(bf16x8 (&aF)[4][2], const bf16_t* rbase,
                                     int wr, int l16, int g) {
  #pragma unroll
  for (int mt = 0; mt < 4; ++mt)
    #pragma unroll
    for (int kk = 0; kk < 2; ++kk)
      aF[mt][kk] = *(const bf16x8*)((const char*)rbase +
          (wr*64 + mt*16 + l16)*128 + ((((kk<<2) ^ g) ^ (l16 & 7)) << 4));
}
__device__ __forceinline__ void rdB2(bf16x8 (&bF)[2][2], const bf16_t* rbase,
                                     int wc, int l16, int g) {
  #pragma unroll
  for (int nt = 0; nt < 2; ++nt)
    #pragma unroll
    for (int kk = 0; kk < 2; ++kk)
      bF[nt][kk] = *(const bf16x8*)((const char*)rbase +
          (wc*32 + nt*16 + l16)*128 + ((((kk<<2) ^ g) ^ (l16 & 7)) << 4));
}

// ---------------------------------------------------------------- 8-phase 256x256 NT GEMM (FFN1)
template<typename OUT_T, bool RELU, bool HAS_RES>
__global__ __launch_bounds__(512, 2)
void gemm8p(const bf16_t* __restrict__ A, const bf16_t* __restrict__ B,
            OUT_T* __restrict__ C, const float* __restrict__ res,
            int M, int N, int K) {
  __shared__ bf16_t sA[2][2][128*64];
  __shared__ bf16_t sB[2][2][128*64];
  const int tid  = threadIdx.x;
  const int lane = tid & 63;
  const int wid  = tid >> 6;
  const int l16  = lane & 15;
  const int g    = lane >> 4;
  const int wr   = wid >> 2;   // 0..1
  const int wc   = wid & 3;    // 0..3

  const int nwg = gridDim.x, bid = blockIdx.x;
  const int qq = nwg >> 3, rr = nwg & 7;
  const int xcd = bid & 7, loc = bid >> 3;
  const int wg = (xcd < rr ? xcd*(qq+1) : rr*(qq+1) + (xcd-rr)*qq) + loc;
  const int nbn = N >> 8;
  const int bm = (wg / nbn) << 8;
  const int bn = (wg % nbn) << 8;

  const int lr  = tid >> 3;                       // 0..63
  const int cq8 = (((tid & 7) ^ (lr & 7)) << 3);

  const size_t aR = (size_t)(bm + lr) * K + cq8;
  const size_t bR = (size_t)(bn + ((lr >> 5) << 6) + (lr & 31)) * K + cq8;
  const size_t rowK128 = (size_t)128 * K, rowK64 = (size_t)64 * K, rowK32 = (size_t)32 * K;

  auto stA = [&](int buf, int mh, int kt) {
    const size_t ko = aR + (size_t)kt * 64 + (size_t)mh * rowK64;
    gload16(A + ko,            &sA[buf][mh][wid*512]);
    gload16(A + ko + rowK128,  &sA[buf][mh][4096 + wid*512]);
  };
  auto stB = [&](int buf, int nh, int kt) {
    const size_t ko = bR + (size_t)kt * 64 + (size_t)nh * rowK32;
    gload16(B + ko,              &sB[buf][nh][wid*512]);
    gload16(B + ko + 2*rowK64,   &sB[buf][nh][4096 + wid*512]);
  };

  f32x4 acc[8][4] = {};
  bf16x8 aF[4][2], bLo[2][2], bHi[2][2];

  stA(0, 0, 0); stB(0, 0, 0); stB(0, 1, 0); stA(0, 1, 0);
  stA(1, 0, 1); stB(1, 0, 1); stB(1, 1, 1);
  VMW(6);
  SBAR();

  const int ni = K >> 7;
  for (int j = 0; j < ni; ++j) {
    const int t1 = 2*j + 1, t2 = 2*j + 2, t3 = 2*j + 3;
    const bool more = (j + 1 < ni);
    rdA4(aF, &sA[0][0][0], wr, l16, g);
    rdB2(bLo, &sB[0][0][0], wc, l16, g);
    stA(1, 1, t1);
    SBAR();
    mm16<0,0>(acc, aF, bLo);
    SBAR();
    rdB2(bHi, &sB[0][1][0], wc, l16, g);
    if (more) stA(0, 0, t2);
    SBAR();
    mm16<0,1>(acc, aF, bHi);
    SBAR();
    rdA4(aF, &sA[0][1][0], wr, l16, g);
    if (more) stB(0, 0, t2);
    SBAR();
    mm16<1,1>(acc, aF, bHi);
    SBAR();
    if (more) { stB(0, 1, t2); VMW(6); } else { VMW(0); }
    SBAR();
    mm16<1,0>(acc, aF, bLo);
    SBAR();
    rdA4(aF, &sA[1][0][0], wr, l16, g);
    rdB2(bLo, &sB[1][0][0], wc, l16, g);
    if (more) stA(0, 1, t2);
    SBAR();
    mm16<0,0>(acc, aF, bLo);
    SBAR();
    rdB2(bHi, &sB[1][1][0], wc, l16, g);
    if (more) stA(1, 0, t3);
    SBAR();
    mm16<0,1>(acc, aF, bHi);
    SBAR();
    rdA4(aF, &sA[1][1][0], wr, l16, g);
    if (more) stB(1, 0, t3);
    SBAR();
    mm16<1,1>(acc, aF, bHi);
    SBAR();
    if (more) { stB(1, 1, t3); VMW(6); }
    SBAR();
    mm16<1,0>(acc, aF, bLo);
    SBAR();
  }

  #pragma unroll
  for (int am = 0; am < 8; ++am) {
    #pragma unroll
    for (int r = 0; r < 4; ++r) {
      const int row = bm + wr*128 + am*16 + g*4 + r;
      #pragma unroll
      for (int an = 0; an < 4; ++an) {
        const int col = bn + wc*64 + an*16 + l16;
        float v = acc[am][an][r];
        if (HAS_RES) v += res[(size_t)row * N + col];
        if (RELU)    v = fmaxf(v, 0.0f);
        C[(size_t)row * N + col] = (OUT_T)v;
      }
    }
  }
}

// ---------------------------------------------------------------- 8-phase 256x128 NT GEMM
template<int MH, int NH>
__device__ __forceinline__ void mm8(f32x4 (&acc)[4][4],
                                    const bf16x8 (&aF)[2][2],
                                    const bf16x8 (&bF)[2][2]) {
  __builtin_amdgcn_s_setprio(1);
  #pragma unroll
  for (int mt = 0; mt < 2; ++mt)
    #pragma unroll
    for (int nt = 0; nt < 2; ++nt)
      #pragma unroll
      for (int kk = 0; kk < 2; ++kk)
        acc[MH*2+mt][NH*2+nt] = __builtin_amdgcn_mfma_f32_16x16x32_bf16(
            aF[mt][kk], bF[nt][kk], acc[MH*2+mt][NH*2+nt], 0, 0, 0);
  __builtin_amdgcn_s_setprio(0);
}

__device__ __forceinline__ void rd2(bf16x8 (&f)[2][2], const bf16_t* rbase,
                                    int wrow, int l16, int g) {
  #pragma unroll
  for (int t = 0; t < 2; ++t)
    #pragma unroll
    for (int kk = 0; kk < 2; ++kk)
      f[t][kk] = *(const bf16x8*)((const char*)rbase +
          (wrow + t*16 + l16)*128 + ((((kk<<2) ^ g) ^ (l16 & 7)) << 4));
}

template<typename OUT_T, bool RELU, bool HAS_RES, int OMODE>
__global__ __launch_bounds__(512, 2)
void gemm8p_n128(const bf16_t* __restrict__ A, const bf16_t* __restrict__ B,
                 OUT_T* __restrict__ C, const void* __restrict__ resv,
                 int M, int N, int K) {
  __shared__ bf16_t sA[2][2][128*64];
  __shared__ bf16_t sB[2][2][64*64];
  const int tid  = threadIdx.x;
  const int lane = tid & 63;
  const int wid  = tid >> 6;
  const int l16  = lane & 15;
  const int g    = lane >> 4;
  const int wr   = wid >> 1;   // 0..3
  const int wc   = wid & 1;    // 0..1

  const int nwg = gridDim.x, bid = blockIdx.x;
  const int qq = nwg >> 3, rr = nwg & 7;
  const int xcd = bid & 7, loc = bid >> 3;
  const int wg = (xcd < rr ? xcd*(qq+1) : rr*(qq+1) + (xcd-rr)*qq) + loc;
  const int nbn = N >> 7;
  const int bm = (wg / nbn) << 8;
  const int bn = (wg % nbn) << 7;

  const int lr  = tid >> 3;                       // 0..63
  const int cq8 = (((tid & 7) ^ (lr & 7)) << 3);
  const size_t aR = (size_t)(bm + ((lr >> 5) << 6) + (lr & 31)) * K + cq8;
  const size_t bR = (size_t)(bn + ((lr >> 5) << 6) + (lr & 31)) * K + cq8;
  const size_t rowK128 = (size_t)128 * K, rowK32 = (size_t)32 * K;

  auto stA = [&](int buf, int mh, int kt) {
    const size_t ko = aR + (size_t)kt * 64 + (size_t)mh * rowK32;
    gload16(A + ko,            &sA[buf][mh][wid*512]);
    gload16(A + ko + rowK128,  &sA[buf][mh][4096 + wid*512]);
  };
  auto stB = [&](int buf, int nh, int kt) {
    gload16(B + bR + (size_t)kt * 64 + (size_t)nh * rowK32, &sB[buf][nh][wid*512]);
  };

  f32x4 acc[4][4] = {};
  bf16x8 aF[2][2], bLo[2][2], bHi[2][2];

  stA(0, 0, 0); stB(0, 0, 0); stB(0, 1, 0); stA(0, 1, 0);
  stA(1, 0, 1); stB(1, 0, 1); stB(1, 1, 1);
  VMW(4);
  SBAR();

  const int ar = wr*32;
  const int br = wc*32;
  const int ni = K >> 7;
  for (int j = 0; j < ni; ++j) {
    const int t1 = 2*j + 1, t2 = 2*j + 2, t3 = 2*j + 3;
    const bool more = (j + 1 < ni);
    rd2(aF,  &sA[0][0][0], ar, l16, g);
    rd2(bLo, &sB[0][0][0], br, l16, g);
    stA(1, 1, t1);
    SBAR();
    mm8<0,0>(acc, aF, bLo);
    SBAR();
    rd2(bHi, &sB[0][1][0], br, l16, g);
    if (more) stA(0, 0, t2);
    SBAR();
    mm8<0,1>(acc, aF, bHi);
    SBAR();
    rd2(aF, &sA[0][1][0], ar, l16, g);
    if (more) stB(0, 0, t2);
    SBAR();
    mm8<1,1>(acc, aF, bHi);
    SBAR();
    if (more) { stB(0, 1, t2); VMW(4); } else { VMW(0); }
    SBAR();
    mm8<1,0>(acc, aF, bLo);
    SBAR();
    rd2(aF,  &sA[1][0][0], ar, l16, g);
    rd2(bLo, &sB[1][0][0], br, l16, g);
    if (more) stA(0, 1, t2);
    SBAR();
    mm8<0,0>(acc, aF, bLo);
    SBAR();
    rd2(bHi, &sB[1][1][0], br, l16, g);
    if (more) stA(1, 0, t3);
    SBAR();
    mm8<0,1>(acc, aF, bHi);
    SBAR();
    rd2(aF, &sA[1][1][0], ar, l16, g);
    if (more) stB(1, 0, t3);
    SBAR();
    mm8<1,1>(acc, aF, bHi);
    SBAR();
    if (more) { stB(1, 1, t3); VMW(4); }
    SBAR();
    mm8<1,0>(acc, aF, bLo);
    SBAR();
  }

  if (OMODE == 2) {
    const int t = bn >> 11;             // 0=q, 1=k, 2=v (wave-uniform)
    const int clb = bn & 2047;
    if (t < 2) {
      bf16_t* base = (bf16_t*)C + (size_t)t * MTOT * DIM;
      #pragma unroll
      for (int am = 0; am < 4; ++am) {
        #pragma unroll
        for (int r = 0; r < 4; ++r) {
          const int row = bm + wr*64 + am*16 + g*4 + r;
          #pragma unroll
          for (int an = 0; an < 4; ++an) {
            const int cl = clb + wc*64 + an*16 + l16;
            base[(size_t)row * DIM + cl] = (bf16_t)acc[am][an][r];
          }
        }
      }
    } else {
      bf16_t* vbase = (bf16_t*)C + (size_t)2 * MTOT * DIM;
      #pragma unroll
      for (int am = 0; am < 4; ++am) {
        const int row = bm + wr*64 + am*16 + g*4;
        #pragma unroll
        for (int an = 0; an < 4; ++an) {
          const int cl = clb + wc*64 + an*16 + l16;
          f32x4 a4 = acc[am][an];
          bf16x4 v4 = {(__bf16)a4[0], (__bf16)a4[1], (__bf16)a4[2], (__bf16)a4[3]};
          *(bf16x4*)(vbase +
              (((size_t)(row >> 11) * NHEADS + (cl >> 7)) * HD + (cl & 127)) * SEQ
              + (row & 2047)) = v4;
        }
      }
    }
  } else {
    const float* resf = (const float*)resv;
    const bf16_t* resb = (const bf16_t*)resv;
    #pragma unroll
    for (int am = 0; am < 4; ++am) {
      #pragma unroll
      for (int r = 0; r < 4; ++r) {
        const int row = bm + wr*64 + am*16 + g*4 + r;
        #pragma unroll
        for (int an = 0; an < 4; ++an) {
          const int col = bn + wc*64 + an*16 + l16;
          float v = acc[am][an][r];
          if (HAS_RES) {
            if (OMODE == 3) v += (float)resb[(size_t)row * N + col];
            else            v += resf[(size_t)row * N + col];
          }
          if (RELU)    v = fmaxf(v, 0.0f);
          C[(size_t)row * N + col] = (OUT_T)v;
        }
      }
    }
  }
}

// ---------------------------------------------------------------- causal flash attention v6
// (measured best: 4 waves, Q-tile 128, 2 blocks/CU, no-max exp2 softmax)
__global__ __launch_bounds__(256, 2)
void attn_k(const bf16_t* __restrict__ Q, const bf16_t* __restrict__ Kk,
            const bf16_t* __restrict__ VT, bf16_t* __restrict__ O) {
  __shared__ bf16_t sK[2][64 * 128];    // [kv][d], chunk-swizzled
  __shared__ bf16_t sVT[2][128 * 64];   // [d][kv], chunk-swizzled
  __shared__ bf16_t sP[4][32 * 64];     // per-wave P, swizzled
  const int tid = threadIdx.x, lane = tid & 63, w = tid >> 6;
  const int l16 = lane & 15, g = lane >> 4;
  const int b = blockIdx.z, h = blockIdx.y;
  const int qt = b ? (SEQ/128 - 1 - blockIdx.x) : blockIdx.x;   // work pairing
  const int ch = h * HD;
  const size_t gb = (size_t)b * SEQ * DIM;
  const int qbase = qt*128 + w*32;
  const bf16_t* VTh = VT + ((size_t)b * NHEADS + h) * ((size_t)HD * SEQ);

  bf16x8 qf[2][4];
  #pragma unroll
  for (int mt = 0; mt < 2; ++mt)
    #pragma unroll
    for (int kb = 0; kb < 4; ++kb)
      qf[mt][kb] = *(const bf16x8*)(Q + gb + (size_t)(qbase + mt*16 + l16)*DIM + ch + kb*32 + g*8);

  const float qs = 0.08838834764831845f * 1.44269504088896f;
  #pragma unroll
  for (int mt = 0; mt < 2; ++mt)
    #pragma unroll
    for (int kb = 0; kb < 4; ++kb)
      #pragma unroll
      for (int e = 0; e < 8; ++e)
        qf[mt][kb][e] = (__bf16)((float)qf[mt][kb][e] * qs);

  f32x4 o[2][8] = {};
  float l_r[2][4];
  #pragma unroll
  for (int mt = 0; mt < 2; ++mt)
    #pragma unroll
    for (int r = 0; r < 4; ++r) l_r[mt][r] = 0.0f;

  const int nsteps = (qt*128 + 128) >> 6;   // KVBLK=64; >= 2

  auto stageK = [&](int buf, int kv0) {
    #pragma unroll
    for (int i = 0; i < 4; ++i) {
      const int c = i*256 + tid;
      const int kv = c >> 4, pos = c & 15;
      const int qsrc = pos ^ (kv & 7);
      gload16(Kk + gb + (size_t)(kv0 + kv)*DIM + ch + (qsrc << 3),
              (char*)sK[buf] + (size_t)(i*256 + w*64)*16);
    }
  };
  auto stageVT = [&](int buf, int kv0) {
    #pragma unroll
    for (int i = 0; i < 4; ++i) {
      const int c = i*256 + tid;
      const int d = c >> 3, p = c & 7;
      const int q = p ^ (d & 7);
      gload16(VTh + (size_t)d * SEQ + kv0 + (q << 3),
              (char*)sVT[buf] + (size_t)(i*256 + w*64)*16);
    }
  };

  stageK(0, 0);  stageVT(0, 0);
  if (nsteps > 1) { stageK(1, 64); stageVT(1, 64); }
  __syncthreads();

  int cur = 0;
  for (int t = 0; t < nsteps; ++t) {
    const int kv0 = t << 6;
    const bool active = (kv0 < qbase + 32);
    if (active) {
      f32x4 s[2][4] = {};
      const char* kb_ = (const char*)sK[cur];
      __builtin_amdgcn_s_setprio(1);
      #pragma unroll
      for (int nt = 0; nt < 4; ++nt) {
        const int row = nt*16 + l16;
        #pragma unroll
        for (int kbi = 0; kbi < 4; ++kbi) {
          const int pos = (kbi*4 + g) ^ (l16 & 7);
          bf16x8 kf = *(const bf16x8*)(kb_ + row*256 + (pos << 4));
          #pragma unroll
          for (int mt = 0; mt < 2; ++mt)
            s[mt][nt] = __builtin_amdgcn_mfma_f32_16x16x32_bf16(qf[mt][kbi], kf, s[mt][nt], 0, 0, 0);
        }
      }
      __builtin_amdgcn_s_setprio(0);

      const bool needmask = (kv0 + 63 > qbase);
      char* pb = (char*)sP[w];
      #pragma unroll
      for (int mt = 0; mt < 2; ++mt) {
        #pragma unroll
        for (int r = 0; r < 4; ++r) {
          const int qpos = qbase + mt*16 + g*4 + r;
          float p[4], rsum = 0.0f;
          #pragma unroll
          for (int nt = 0; nt < 4; ++nt) {
            float sv = s[mt][nt][r];
            if (needmask && (kv0 + nt*16 + l16 > qpos)) sv = -1e9f;
            p[nt] = exp2f(sv);
            rsum += p[nt];
          }
          #pragma unroll
          for (int d = 8; d >= 1; d >>= 1) rsum += __shfl_xor(rsum, d, 16);
          l_r[mt][r] += rsum;
          const int prow = mt*16 + g*4 + r;
          #pragma unroll
          for (int nt = 0; nt < 4; ++nt)
            *(bf16_t*)(pb + ((prow*128 + nt*32 + l16*2) ^ (g << 5))) = (bf16_t)p[nt];
        }
      }

      bf16x8 pa[2][2];
      #pragma unroll
      for (int mt = 0; mt < 2; ++mt) {
        const int row2 = mt*16 + l16;
        #pragma unroll
        for (int ks = 0; ks < 2; ++ks)
          pa[mt][ks] = *(const bf16x8*)((const char*)sP[w] +
                    ((row2*128 + ks*64 + g*16) ^ (((l16 >> 2) & 3) << 5)));
      }

      const char* vb_ = (const char*)sVT[cur];
      __builtin_amdgcn_s_setprio(1);
      #pragma unroll
      for (int dt = 0; dt < 8; ++dt) {
        const int d = dt*16 + l16;
        #pragma unroll
        for (int ks = 0; ks < 2; ++ks) {
          const int pos = (ks*4 + g) ^ (d & 7);
          bf16x8 vf = *(const bf16x8*)(vb_ + d*128 + (pos << 4));
          #pragma unroll
          for (int mt = 0; mt < 2; ++mt)
            o[mt][dt] = __builtin_amdgcn_mfma_f32_16x16x32_bf16(pa[mt][ks], vf, o[mt][dt], 0, 0, 0);
        }
      }
      __builtin_amdgcn_s_setprio(0);
    }
    __syncthreads();
    if (t + 2 < nsteps) {
      stageK(cur, (t + 2) << 6);
      stageVT(cur, (t + 2) << 6);
    }
    cur ^= 1;
  }

  #pragma unroll
  for (int mt = 0; mt < 2; ++mt) {
    #pragma unroll
    for (int r = 0; r < 4; ++r) {
      const float inv = 1.0f / l_r[mt][r];
      const int row = qbase + mt*16 + g*4 + r;
      #pragma unroll
      for (int dt = 0; dt < 8; ++dt)
        O[gb + (size_t)row*DIM + ch + dt*16 + l16] = (bf16_t)(o[mt][dt][r] * inv);
    }
  }
}

// ---------------------------------------------------------------- launcher
extern "C" void kernel_launch(void* const* d_in, const int* in_sizes, int n_in,
                              void* d_out, int out_size, void* d_ws, size_t ws_size,
                              hipStream_t stream) {
  const float* x   = (const float*)d_in[0];
  const float* wq  = (const float*)d_in[2];
  const float* wk  = (const float*)d_in[3];
  const float* wv  = (const float*)d_in[4];
  const float* wo  = (const float*)d_in[5];
  const float* w1  = (const float*)d_in[6];
  const float* w2  = (const float*)d_in[7];
  const float* anw = (const float*)d_in[8];
  const float* fnw = (const float*)d_in[9];
  float* out = (float*)d_out;

  char* p = (char*)d_ws;
  bf16_t* wqb = (bf16_t*)p; p += (size_t)DIM*DIM*2*4;      // wq|wk|wv|wo contiguous
  bf16_t* w1b = (bf16_t*)p; p += (size_t)DIM*HIDDEN*2;
  bf16_t* w2b = (bf16_t*)p; p += (size_t)DIM*HIDDEN*2;
  bf16_t* xn  = (bf16_t*)p; p += (size_t)MTOT*DIM*2;
  bf16_t* hb  = (bf16_t*)p; p += (size_t)MTOT*DIM*2;       // h residual, bf16
  bf16_t* big = (bf16_t*)p; p += (size_t)MTOT*HIDDEN*2;

  bf16_t* wob = wqb + 3*(size_t)DIM*DIM;
  bf16_t* qb = big;
  bf16_t* kb = big + (size_t)MTOT*DIM;
  bf16_t* vT = big + 2*(size_t)MTOT*DIM;   // [B][H][HD][SEQ]
  bf16_t* ab = big + 3*(size_t)MTOT*DIM;
  bf16_t* f1 = big;

  // fused weight-cvt + rmsnorm1
  cvtrms_k<<<MTOT + 4096, 256, 0, stream>>>(x, anw, xn, wq, wk, wv, wo, w1, w2, wqb);

  // fused QKV: one 256x128 GEMM over N=6144
  gemm8p_n128<bf16_t, false, false, 2><<<768, 512, 0, stream>>>(
      xn, wqb, qb, nullptr, MTOT, 3*DIM, DIM);

  attn_k<<<dim3(SEQ/128, NHEADS, BSZ), 256, 0, stream>>>(qb, kb, vT, ab);

  // WO + x residual -> h (bf16)
  gemm8p_n128<bf16_t, false, true, 0><<<256, 512, 0, stream>>>(
      ab, wob, hb, x, MTOT, DIM, DIM);

  rmsnorm_bf_k<<<MTOT, 256, 0, stream>>>(hb, fnw, xn);

  gemm8p<bf16_t, true, false><<<512, 512, 0, stream>>>(
      xn, w1b, f1, nullptr, MTOT, HIDDEN, DIM);

  // FFN2 + h residual (bf16) -> out fp32
  gemm8p_n128<float, false, true, 3><<<256, 512, 0, stream>>>(
      f1, w2b, out, hb, MTOT, DIM, HIDDEN);
}

// Round 20
// 575.700 us; speedup vs baseline: 1.0597x; 1.0597x over previous
//
#include <hip/hip_runtime.h>
#include <cstdint>
#include <cstddef>

#define DIM 2048
#define NHEADS 16
#define HD 128
#define HIDDEN 8192
#define BSZ 2
#define SEQ 2048
#define MTOT (BSZ*SEQ)   // 4096 rows total

typedef __bf16 bf16_t;
typedef __bf16 bf16x8 __attribute__((ext_vector_type(8)));
typedef __bf16 bf16x4 __attribute__((ext_vector_type(4)));
typedef float  f32x4  __attribute__((ext_vector_type(4)));

// async global->LDS, 16B per lane. LDS dest must be the WAVE-UNIFORM base;
// HW adds lane*16. Global src is per-lane.
__device__ __forceinline__ void gload16(const void* g, void* lds) {
  __builtin_amdgcn_global_load_lds(
      (const __attribute__((address_space(1))) uint32_t*)g,
      (__attribute__((address_space(3))) uint32_t*)lds, 16, 0, 0);
}

// Barrier discipline A/B results (measured):
//   r10 clobbered BAR/VMW everywhere ........ 648-class
//   r12 full sched_barrier pinning .......... 666
//   r16/r18 bare SBAR + PIN-before-stage .... 576  <= best, keep
//   r19 no PIN at all ....................... 610
#define SBAR() __builtin_amdgcn_s_barrier()
#define PIN()  __builtin_amdgcn_sched_barrier(0)
#define VMW(N) asm volatile("s_waitcnt vmcnt(" #N ")")

// ---------------------------------------------------------------- fused cvt + rmsnorm1
__global__ __launch_bounds__(256)
void cvtrms_k(const float* __restrict__ x, const float* __restrict__ wt,
              bf16_t* __restrict__ xn,
              const float* __restrict__ wq, const float* __restrict__ wk,
              const float* __restrict__ wv, const float* __restrict__ wo,
              const float* __restrict__ w1, const float* __restrict__ w2,
              bf16_t* __restrict__ wdst) {
  const int tid = threadIdx.x;
  if (blockIdx.x < MTOT) {
    const int row = blockIdx.x;
    const float* xr = x + (size_t)row * DIM;
    float4 a = ((const float4*)xr)[tid];
    float4 b = ((const float4*)xr)[tid + 256];
    float ss = a.x*a.x + a.y*a.y + a.z*a.z + a.w*a.w
             + b.x*b.x + b.y*b.y + b.z*b.z + b.w*b.w;
    #pragma unroll
    for (int d = 32; d >= 1; d >>= 1) ss += __shfl_xor(ss, d, 64);
    __shared__ float red[4];
    if ((tid & 63) == 0) red[tid >> 6] = ss;
    __syncthreads();
    float tot = red[0] + red[1] + red[2] + red[3];
    float rs = rsqrtf(tot * (1.0f / DIM) + 1e-6f);
    float4 wa = ((const float4*)wt)[tid];
    float4 wb = ((const float4*)wt)[tid + 256];
    bf16x4 oa = {(__bf16)(a.x*rs*wa.x), (__bf16)(a.y*rs*wa.y),
                 (__bf16)(a.z*rs*wa.z), (__bf16)(a.w*rs*wa.w)};
    bf16x4 ob = {(__bf16)(b.x*rs*wb.x), (__bf16)(b.y*rs*wb.y),
                 (__bf16)(b.z*rs*wb.z), (__bf16)(b.w*rs*wb.w)};
    *(bf16x4*)(xn + (size_t)row*DIM + tid*4)        = oa;
    *(bf16x4*)(xn + (size_t)row*DIM + 1024 + tid*4) = ob;
    return;
  }
  const int S1 = (DIM*DIM) >> 2;
  const int S2 = (DIM*HIDDEN) >> 2;
  const int total = 4*S1 + 2*S2;
  int i = (blockIdx.x - MTOT) * blockDim.x + tid;
  const int stride = (gridDim.x - MTOT) * blockDim.x;
  for (; i < total; i += stride) {
    const float* src; int off;
    if (i < 4*S1) {
      const int r = i >> 20; off = i & (S1 - 1);
      src = (r == 0) ? wq : (r == 1) ? wk : (r == 2) ? wv : wo;
    } else {
      const int j = i - 4*S1;
      if (j < S2) { src = w1; off = j; } else { src = w2; off = j - S2; }
    }
    float4 v = ((const float4*)src)[off];
    bf16x4 o = {(__bf16)v.x, (__bf16)v.y, (__bf16)v.z, (__bf16)v.w};
    ((bf16x4*)wdst)[i] = o;
  }
}

// ---------------------------------------------------------------- RMSNorm (bf16 in -> bf16 out)
__global__ __launch_bounds__(256)
void rmsnorm_bf_k(const bf16_t* __restrict__ h, const float* __restrict__ wt,
                  bf16_t* __restrict__ out) {
  const int row = blockIdx.x;
  const int tid = threadIdx.x;
  bf16x8 v = *(const bf16x8*)(h + (size_t)row*DIM + tid*8);
  float f[8];
  float ss = 0.0f;
  #pragma unroll
  for (int e = 0; e < 8; ++e) { f[e] = (float)v[e]; ss += f[e]*f[e]; }
  #pragma unroll
  for (int d = 32; d >= 1; d >>= 1) ss += __shfl_xor(ss, d, 64);
  __shared__ float red[4];
  if ((tid & 63) == 0) red[tid >> 6] = ss;
  __syncthreads();
  float tot = red[0] + red[1] + red[2] + red[3];
  float rs = rsqrtf(tot * (1.0f / DIM) + 1e-6f);
  float4 wa = ((const float4*)wt)[tid*2];
  float4 wb = ((const float4*)wt)[tid*2 + 1];
  bf16x8 o;
  o[0] = (__bf16)(f[0]*rs*wa.x); o[1] = (__bf16)(f[1]*rs*wa.y);
  o[2] = (__bf16)(f[2]*rs*wa.z); o[3] = (__bf16)(f[3]*rs*wa.w);
  o[4] = (__bf16)(f[4]*rs*wb.x); o[5] = (__bf16)(f[5]*rs*wb.y);
  o[6] = (__bf16)(f[6]*rs*wb.z); o[7] = (__bf16)(f[7]*rs*wb.w);
  *(bf16x8*)(out + (size_t)row*DIM + tid*8) = o;
}

// ---------------------------------------------------------------- 8-phase GEMM helpers (256x256)
template<int MH, int NH>
__device__ __forceinline__ void mm16(f32x4 (&acc)[8][4],
                                     const bf16x8 (&aF)[4][2],
                                     const bf16x8 (&bF)[2][2]) {
  __builtin_amdgcn_s_setprio(1);
  #pragma unroll
  for (int mt = 0; mt < 4; ++mt)
    #pragma unroll
    for (int nt = 0; nt < 2; ++nt)
      #pragma unroll
      for (int kk = 0; kk < 2; ++kk)
        acc[MH*4+mt][NH*2+nt] = __builtin_amdgcn_mfma_f32_16x16x32_bf16(
            aF[mt][kk], bF[nt][kk], acc[MH*4+mt][NH*2+nt], 0, 0, 0);
  __builtin_amdgcn_s_setprio(0);
}

__device__ __forceinline__ void rdA4(bf16x8 (&aF)[4][2], const bf16_t* rbase,
                                     int wr, int l16, int g) {
  #pragma unroll
  for (int mt = 0; mt < 4; ++mt)
    #pragma unroll
    for (int kk = 0; kk < 2; ++kk)
      aF[mt][kk] = *(const bf16x8*)((const char*)rbase +
          (wr*64 + mt*16 + l16)*128 + ((((kk<<2) ^ g) ^ (l16 & 7)) << 4));
}
__device__ __forceinline__ void rdB2(bf16x8 (&bF)[2][2], const bf16_t* rbase,
                                     int wc, int l16, int g) {
  #pragma unroll
  for (int nt = 0; nt < 2; ++nt)
    #pragma unroll
    for (int kk = 0; kk < 2; ++kk)
      bF[nt][kk] = *(const bf16x8*)((const char*)rbase +
          (wc*32 + nt*16 + l16)*128 + ((((kk<<2) ^ g) ^ (l16 & 7)) << 4));
}

// ---------------------------------------------------------------- 8-phase 256x256 NT GEMM (FFN1)
template<typename OUT_T, bool RELU, bool HAS_RES>
__global__ __launch_bounds__(512, 2)
void gemm8p(const bf16_t* __restrict__ A, const bf16_t* __restrict__ B,
            OUT_T* __restrict__ C, const float* __restrict__ res,
            int M, int N, int K) {
  __shared__ bf16_t sA[2][2][128*64];
  __shared__ bf16_t sB[2][2][128*64];
  const int tid  = threadIdx.x;
  const int lane = tid & 63;
  const int wid  = tid >> 6;
  const int l16  = lane & 15;
  const int g    = lane >> 4;
  const int wr   = wid >> 2;   // 0..1
  const int wc   = wid & 3;    // 0..3

  const int nwg = gridDim.x, bid = blockIdx.x;
  const int qq = nwg >> 3, rr = nwg & 7;
  const int xcd = bid & 7, loc = bid >> 3;
  const int wg = (xcd < rr ? xcd*(qq+1) : rr*(qq+1) + (xcd-rr)*qq) + loc;
  const int nbn = N >> 8;
  const int bm = (wg / nbn) << 8;
  const int bn = (wg % nbn) << 8;

  const int lr  = tid >> 3;                       // 0..63
  const int cq8 = (((tid & 7) ^ (lr & 7)) << 3);

  const size_t aR = (size_t)(bm + lr) * K + cq8;
  const size_t bR = (size_t)(bn + ((lr >> 5) << 6) + (lr & 31)) * K + cq8;
  const size_t rowK128 = (size_t)128 * K, rowK64 = (size_t)64 * K, rowK32 = (size_t)32 * K;

  auto stA = [&](int buf, int mh, int kt) {
    const size_t ko = aR + (size_t)kt * 64 + (size_t)mh * rowK64;
    gload16(A + ko,            &sA[buf][mh][wid*512]);
    gload16(A + ko + rowK128,  &sA[buf][mh][4096 + wid*512]);
  };
  auto stB = [&](int buf, int nh, int kt) {
    const size_t ko = bR + (size_t)kt * 64 + (size_t)nh * rowK32;
    gload16(B + ko,              &sB[buf][nh][wid*512]);
    gload16(B + ko + 2*rowK64,   &sB[buf][nh][4096 + wid*512]);
  };

  f32x4 acc[8][4] = {};
  bf16x8 aF[4][2], bLo[2][2], bHi[2][2];

  stA(0, 0, 0); stB(0, 0, 0); stB(0, 1, 0); stA(0, 1, 0);
  stA(1, 0, 1); stB(1, 0, 1); stB(1, 1, 1);
  VMW(6);
  SBAR();

  const int ni = K >> 7;
  for (int j = 0; j < ni; ++j) {
    const int t1 = 2*j + 1, t2 = 2*j + 2, t3 = 2*j + 3;
    const bool more = (j + 1 < ni);
    rdA4(aF, &sA[0][0][0], wr, l16, g);
    rdB2(bLo, &sB[0][0][0], wc, l16, g);
    PIN(); stA(1, 1, t1);
    SBAR();
    mm16<0,0>(acc, aF, bLo);
    SBAR();
    rdB2(bHi, &sB[0][1][0], wc, l16, g);
    PIN(); if (more) stA(0, 0, t2);
    SBAR();
    mm16<0,1>(acc, aF, bHi);
    SBAR();
    rdA4(aF, &sA[0][1][0], wr, l16, g);
    PIN(); if (more) stB(0, 0, t2);
    SBAR();
    mm16<1,1>(acc, aF, bHi);
    SBAR();
    PIN();
    if (more) { stB(0, 1, t2); VMW(6); } else { VMW(0); }
    SBAR();
    mm16<1,0>(acc, aF, bLo);
    SBAR();
    rdA4(aF, &sA[1][0][0], wr, l16, g);
    rdB2(bLo, &sB[1][0][0], wc, l16, g);
    PIN(); if (more) stA(0, 1, t2);
    SBAR();
    mm16<0,0>(acc, aF, bLo);
    SBAR();
    rdB2(bHi, &sB[1][1][0], wc, l16, g);
    PIN(); if (more) stA(1, 0, t3);
    SBAR();
    mm16<0,1>(acc, aF, bHi);
    SBAR();
    rdA4(aF, &sA[1][1][0], wr, l16, g);
    PIN(); if (more) stB(1, 0, t3);
    SBAR();
    mm16<1,1>(acc, aF, bHi);
    SBAR();
    PIN();
    if (more) { stB(1, 1, t3); VMW(6); }
    SBAR();
    mm16<1,0>(acc, aF, bLo);
    SBAR();
  }

  #pragma unroll
  for (int am = 0; am < 8; ++am) {
    #pragma unroll
    for (int r = 0; r < 4; ++r) {
      const int row = bm + wr*128 + am*16 + g*4 + r;
      #pragma unroll
      for (int an = 0; an < 4; ++an) {
        const int col = bn + wc*64 + an*16 + l16;
        float v = acc[am][an][r];
        if (HAS_RES) v += res[(size_t)row * N + col];
        if (RELU)    v = fmaxf(v, 0.0f);
        C[(size_t)row * N + col] = (OUT_T)v;
      }
    }
  }
}

// ---------------------------------------------------------------- 8-phase 256x128 NT GEMM
template<int MH, int NH>
__device__ __forceinline__ void mm8(f32x4 (&acc)[4][4],
                                    const bf16x8 (&aF)[2][2],
                                    const bf16x8 (&bF)[2][2]) {
  __builtin_amdgcn_s_setprio(1);
  #pragma unroll
  for (int mt = 0; mt < 2; ++mt)
    #pragma unroll
    for (int nt = 0; nt < 2; ++nt)
      #pragma unroll
      for (int kk = 0; kk < 2; ++kk)
        acc[MH*2+mt][NH*2+nt] = __builtin_amdgcn_mfma_f32_16x16x32_bf16(
            aF[mt][kk], bF[nt][kk], acc[MH*2+mt][NH*2+nt], 0, 0, 0);
  __builtin_amdgcn_s_setprio(0);
}

__device__ __forceinline__ void rd2(bf16x8 (&f)[2][2], const bf16_t* rbase,
                                    int wrow, int l16, int g) {
  #pragma unroll
  for (int t = 0; t < 2; ++t)
    #pragma unroll
    for (int kk = 0; kk < 2; ++kk)
      f[t][kk] = *(const bf16x8*)((const char*)rbase +
          (wrow + t*16 + l16)*128 + ((((kk<<2) ^ g) ^ (l16 & 7)) << 4));
}

template<typename OUT_T, bool RELU, bool HAS_RES, int OMODE>
__global__ __launch_bounds__(512, 2)
void gemm8p_n128(const bf16_t* __restrict__ A, const bf16_t* __restrict__ B,
                 OUT_T* __restrict__ C, const void* __restrict__ resv,
                 int M, int N, int K) {
  __shared__ bf16_t sA[2][2][128*64];
  __shared__ bf16_t sB[2][2][64*64];
  const int tid  = threadIdx.x;
  const int lane = tid & 63;
  const int wid  = tid >> 6;
  const int l16  = lane & 15;
  const int g    = lane >> 4;
  const int wr   = wid >> 1;   // 0..3
  const int wc   = wid & 1;    // 0..1

  const int nwg = gridDim.x, bid = blockIdx.x;
  const int qq = nwg >> 3, rr = nwg & 7;
  const int xcd = bid & 7, loc = bid >> 3;
  const int wg = (xcd < rr ? xcd*(qq+1) : rr*(qq+1) + (xcd-rr)*qq) + loc;
  const int nbn = N >> 7;
  const int bm = (wg / nbn) << 8;
  const int bn = (wg % nbn) << 7;

  const int lr  = tid >> 3;                       // 0..63
  const int cq8 = (((tid & 7) ^ (lr & 7)) << 3);
  const size_t aR = (size_t)(bm + ((lr >> 5) << 6) + (lr & 31)) * K + cq8;
  const size_t bR = (size_t)(bn + ((lr >> 5) << 6) + (lr & 31)) * K + cq8;
  const size_t rowK128 = (size_t)128 * K, rowK32 = (size_t)32 * K;

  auto stA = [&](int buf, int mh, int kt) {
    const size_t ko = aR + (size_t)kt * 64 + (size_t)mh * rowK32;
    gload16(A + ko,            &sA[buf][mh][wid*512]);
    gload16(A + ko + rowK128,  &sA[buf][mh][4096 + wid*512]);
  };
  auto stB = [&](int buf, int nh, int kt) {
    gload16(B + bR + (size_t)kt * 64 + (size_t)nh * rowK32, &sB[buf][nh][wid*512]);
  };

  f32x4 acc[4][4] = {};
  bf16x8 aF[2][2], bLo[2][2], bHi[2][2];

  stA(0, 0, 0); stB(0, 0, 0); stB(0, 1, 0); stA(0, 1, 0);
  stA(1, 0, 1); stB(1, 0, 1); stB(1, 1, 1);
  VMW(4);
  SBAR();

  const int ar = wr*32;
  const int br = wc*32;
  const int ni = K >> 7;
  for (int j = 0; j < ni; ++j) {
    const int t1 = 2*j + 1, t2 = 2*j + 2, t3 = 2*j + 3;
    const bool more = (j + 1 < ni);
    rd2(aF,  &sA[0][0][0], ar, l16, g);
    rd2(bLo, &sB[0][0][0], br, l16, g);
    PIN(); stA(1, 1, t1);
    SBAR();
    mm8<0,0>(acc, aF, bLo);
    SBAR();
    rd2(bHi, &sB[0][1][0], br, l16, g);
    PIN(); if (more) stA(0, 0, t2);
    SBAR();
    mm8<0,1>(acc, aF, bHi);
    SBAR();
    rd2(aF, &sA[0][1][0], ar, l16, g);
    PIN(); if (more) stB(0, 0, t2);
    SBAR();
    mm8<1,1>(acc, aF, bHi);
    SBAR();
    PIN();
    if (more) { stB(0, 1, t2); VMW(4); } else { VMW(0); }
    SBAR();
    mm8<1,0>(acc, aF, bLo);
    SBAR();
    rd2(aF,  &sA[1][0][0], ar, l16, g);
    rd2(bLo, &sB[1][0][0], br, l16, g);
    PIN(); if (more) stA(0, 1, t2);
    SBAR();
    mm8<0,0>(acc, aF, bLo);
    SBAR();
    rd2(bHi, &sB[1][1][0], br, l16, g);
    PIN(); if (more) stA(1, 0, t3);
    SBAR();
    mm8<0,1>(acc, aF, bHi);
    SBAR();
    rd2(aF, &sA[1][1][0], ar, l16, g);
    PIN(); if (more) stB(1, 0, t3);
    SBAR();
    mm8<1,1>(acc, aF, bHi);
    SBAR();
    PIN();
    if (more) { stB(1, 1, t3); VMW(4); }
    SBAR();
    mm8<1,0>(acc, aF, bLo);
    SBAR();
  }

  if (OMODE == 2) {
    const int t = bn >> 11;             // 0=q, 1=k, 2=v (wave-uniform)
    const int clb = bn & 2047;
    if (t < 2) {
      bf16_t* base = (bf16_t*)C + (size_t)t * MTOT * DIM;
      #pragma unroll
      for (int am = 0; am < 4; ++am) {
        #pragma unroll
        for (int r = 0; r < 4; ++r) {
          const int row = bm + wr*64 + am*16 + g*4 + r;
          #pragma unroll
          for (int an = 0; an < 4; ++an) {
            const int cl = clb + wc*64 + an*16 + l16;
            base[(size_t)row * DIM + cl] = (bf16_t)acc[am][an][r];
          }
        }
      }
    } else {
      bf16_t* vbase = (bf16_t*)C + (size_t)2 * MTOT * DIM;
      #pragma unroll
      for (int am = 0; am < 4; ++am) {
        const int row = bm + wr*64 + am*16 + g*4;
        #pragma unroll
        for (int an = 0; an < 4; ++an) {
          const int cl = clb + wc*64 + an*16 + l16;
          f32x4 a4 = acc[am][an];
          bf16x4 v4 = {(__bf16)a4[0], (__bf16)a4[1], (__bf16)a4[2], (__bf16)a4[3]};
          *(bf16x4*)(vbase +
              (((size_t)(row >> 11) * NHEADS + (cl >> 7)) * HD + (cl & 127)) * SEQ
              + (row & 2047)) = v4;
        }
      }
    }
  } else {
    const float* resf = (const float*)resv;
    const bf16_t* resb = (const bf16_t*)resv;
    #pragma unroll
    for (int am = 0; am < 4; ++am) {
      #pragma unroll
      for (int r = 0; r < 4; ++r) {
        const int row = bm + wr*64 + am*16 + g*4 + r;
        #pragma unroll
        for (int an = 0; an < 4; ++an) {
          const int col = bn + wc*64 + an*16 + l16;
          float v = acc[am][an][r];
          if (HAS_RES) {
            if (OMODE == 3) v += (float)resb[(size_t)row * N + col];
            else            v += resf[(size_t)row * N + col];
          }
          if (RELU)    v = fmaxf(v, 0.0f);
          C[(size_t)row * N + col] = (OUT_T)v;
        }
      }
    }
  }
}

// ---------------------------------------------------------------- causal flash attention v6
// (measured best: 4 waves, Q-tile 128, 2 blocks/CU, no-max exp2 softmax)
__global__ __launch_bounds__(256, 2)
void attn_k(const bf16_t* __restrict__ Q, const bf16_t* __restrict__ Kk,
            const bf16_t* __restrict__ VT, bf16_t* __restrict__ O) {
  __shared__ bf16_t sK[2][64 * 128];    // [kv][d], chunk-swizzled
  __shared__ bf16_t sVT[2][128 * 64];   // [d][kv], chunk-swizzled
  __shared__ bf16_t sP[4][32 * 64];     // per-wave P, swizzled
  const int tid = threadIdx.x, lane = tid & 63, w = tid >> 6;
  const int l16 = lane & 15, g = lane >> 4;
  const int b = blockIdx.z, h = blockIdx.y;
  const int qt = b ? (SEQ/128 - 1 - blockIdx.x) : blockIdx.x;   // work pairing
  const int ch = h * HD;
  const size_t gb = (size_t)b * SEQ * DIM;
  const int qbase = qt*128 + w*32;
  const bf16_t* VTh = VT + ((size_t)b * NHEADS + h) * ((size_t)HD * SEQ);

  bf16x8 qf[2][4];
  #pragma unroll
  for (int mt = 0; mt < 2; ++mt)
    #pragma unroll
    for (int kb = 0; kb < 4; ++kb)
      qf[mt][kb] = *(const bf16x8*)(Q + gb + (size_t)(qbase + mt*16 + l16)*DIM + ch + kb*32 + g*8);

  const float qs = 0.08838834764831845f * 1.44269504088896f;
  #pragma unroll
  for (int mt = 0; mt < 2; ++mt)
    #pragma unroll
    for (int kb = 0; kb < 4; ++kb)
      #pragma unroll
      for (int e = 0; e < 8; ++e)
        qf[mt][kb][e] = (__bf16)((float)qf[mt][kb][e] * qs);

  f32x4 o[2][8] = {};
  float l_r[2][4];
  #pragma unroll
  for (int mt = 0; mt < 2; ++mt)
    #pragma unroll
    for (int r = 0; r < 4; ++r) l_r[mt][r] = 0.0f;

  const int nsteps = (qt*128 + 128) >> 6;   // KVBLK=64; >= 2

  auto stageK = [&](int buf, int kv0) {
    #pragma unroll
    for (int i = 0; i < 4; ++i) {
      const int c = i*256 + tid;
      const int kv = c >> 4, pos = c & 15;
      const int qsrc = pos ^ (kv & 7);
      gload16(Kk + gb + (size_t)(kv0 + kv)*DIM + ch + (qsrc << 3),
              (char*)sK[buf] + (size_t)(i*256 + w*64)*16);
    }
  };
  auto stageVT = [&](int buf, int kv0) {
    #pragma unroll
    for (int i = 0; i < 4; ++i) {
      const int c = i*256 + tid;
      const int d = c >> 3, p = c & 7;
      const int q = p ^ (d & 7);
      gload16(VTh + (size_t)d * SEQ + kv0 + (q << 3),
              (char*)sVT[buf] + (size_t)(i*256 + w*64)*16);
    }
  };

  stageK(0, 0);  stageVT(0, 0);
  if (nsteps > 1) { stageK(1, 64); stageVT(1, 64); }
  __syncthreads();

  int cur = 0;
  for (int t = 0; t < nsteps; ++t) {
    const int kv0 = t << 6;
    const bool active = (kv0 < qbase + 32);
    if (active) {
      f32x4 s[2][4] = {};
      const char* kb_ = (const char*)sK[cur];
      __builtin_amdgcn_s_setprio(1);
      #pragma unroll
      for (int nt = 0; nt < 4; ++nt) {
        const int row = nt*16 + l16;
        #pragma unroll
        for (int kbi = 0; kbi < 4; ++kbi) {
          const int pos = (kbi*4 + g) ^ (l16 & 7);
          bf16x8 kf = *(const bf16x8*)(kb_ + row*256 + (pos << 4));
          #pragma unroll
          for (int mt = 0; mt < 2; ++mt)
            s[mt][nt] = __builtin_amdgcn_mfma_f32_16x16x32_bf16(qf[mt][kbi], kf, s[mt][nt], 0, 0, 0);
        }
      }
      __builtin_amdgcn_s_setprio(0);

      const bool needmask = (kv0 + 63 > qbase);
      char* pb = (char*)sP[w];
      #pragma unroll
      for (int mt = 0; mt < 2; ++mt) {
        #pragma unroll
        for (int r = 0; r < 4; ++r) {
          const int qpos = qbase + mt*16 + g*4 + r;
          float p[4], rsum = 0.0f;
          #pragma unroll
          for (int nt = 0; nt < 4; ++nt) {
            float sv = s[mt][nt][r];
            if (needmask && (kv0 + nt*16 + l16 > qpos)) sv = -1e9f;
            p[nt] = exp2f(sv);
            rsum += p[nt];
          }
          #pragma unroll
          for (int d = 8; d >= 1; d >>= 1) rsum += __shfl_xor(rsum, d, 16);
          l_r[mt][r] += rsum;
          const int prow = mt*16 + g*4 + r;
          #pragma unroll
          for (int nt = 0; nt < 4; ++nt)
            *(bf16_t*)(pb + ((prow*128 + nt*32 + l16*2) ^ (g << 5))) = (bf16_t)p[nt];
        }
      }

      bf16x8 pa[2][2];
      #pragma unroll
      for (int mt = 0; mt < 2; ++mt) {
        const int row2 = mt*16 + l16;
        #pragma unroll
        for (int ks = 0; ks < 2; ++ks)
          pa[mt][ks] = *(const bf16x8*)((const char*)sP[w] +
                    ((row2*128 + ks*64 + g*16) ^ (((l16 >> 2) & 3) << 5)));
      }

      const char* vb_ = (const char*)sVT[cur];
      __builtin_amdgcn_s_setprio(1);
      #pragma unroll
      for (int dt = 0; dt < 8; ++dt) {
        const int d = dt*16 + l16;
        #pragma unroll
        for (int ks = 0; ks < 2; ++ks) {
          const int pos = (ks*4 + g) ^ (d & 7);
          bf16x8 vf = *(const bf16x8*)(vb_ + d*128 + (pos << 4));
          #pragma unroll
          for (int mt = 0; mt < 2; ++mt)
            o[mt][dt] = __builtin_amdgcn_mfma_f32_16x16x32_bf16(pa[mt][ks], vf, o[mt][dt], 0, 0, 0);
        }
      }
      __builtin_amdgcn_s_setprio(0);
    }
    __syncthreads();
    if (t + 2 < nsteps) {
      stageK(cur, (t + 2) << 6);
      stageVT(cur, (t + 2) << 6);
    }
    cur ^= 1;
  }

  #pragma unroll
  for (int mt = 0; mt < 2; ++mt) {
    #pragma unroll
    for (int r = 0; r < 4; ++r) {
      const float inv = 1.0f / l_r[mt][r];
      const int row = qbase + mt*16 + g*4 + r;
      #pragma unroll
      for (int dt = 0; dt < 8; ++dt)
        O[gb + (size_t)row*DIM + ch + dt*16 + l16] = (bf16_t)(o[mt][dt][r] * inv);
    }
  }
}

// ---------------------------------------------------------------- launcher
extern "C" void kernel_launch(void* const* d_in, const int* in_sizes, int n_in,
                              void* d_out, int out_size, void* d_ws, size_t ws_size,
                              hipStream_t stream) {
  const float* x   = (const float*)d_in[0];
  const float* wq  = (const float*)d_in[2];
  const float* wk  = (const float*)d_in[3];
  const float* wv  = (const float*)d_in[4];
  const float* wo  = (const float*)d_in[5];
  const float* w1  = (const float*)d_in[6];
  const float* w2  = (const float*)d_in[7];
  const float* anw = (const float*)d_in[8];
  const float* fnw = (const float*)d_in[9];
  float* out = (float*)d_out;

  char* p = (char*)d_ws;
  bf16_t* wqb = (bf16_t*)p; p += (size_t)DIM*DIM*2*4;      // wq|wk|wv|wo contiguous
  bf16_t* w1b = (bf16_t*)p; p += (size_t)DIM*HIDDEN*2;
  bf16_t* w2b = (bf16_t*)p; p += (size_t)DIM*HIDDEN*2;
  bf16_t* xn  = (bf16_t*)p; p += (size_t)MTOT*DIM*2;
  bf16_t* hb  = (bf16_t*)p; p += (size_t)MTOT*DIM*2;       // h residual, bf16
  bf16_t* big = (bf16_t*)p; p += (size_t)MTOT*HIDDEN*2;

  bf16_t* wob = wqb + 3*(size_t)DIM*DIM;
  bf16_t* qb = big;
  bf16_t* kb = big + (size_t)MTOT*DIM;
  bf16_t* vT = big + 2*(size_t)MTOT*DIM;   // [B][H][HD][SEQ]
  bf16_t* ab = big + 3*(size_t)MTOT*DIM;
  bf16_t* f1 = big;

  // fused weight-cvt + rmsnorm1
  cvtrms_k<<<MTOT + 4096, 256, 0, stream>>>(x, anw, xn, wq, wk, wv, wo, w1, w2, wqb);

  // fused QKV: one 256x128 GEMM over N=6144
  gemm8p_n128<bf16_t, false, false, 2><<<768, 512, 0, stream>>>(
      xn, wqb, qb, nullptr, MTOT, 3*DIM, DIM);

  attn_k<<<dim3(SEQ/128, NHEADS, BSZ), 256, 0, stream>>>(qb, kb, vT, ab);

  // WO + x residual -> h (bf16)
  gemm8p_n128<bf16_t, false, true, 0><<<256, 512, 0, stream>>>(
      ab, wob, hb, x, MTOT, DIM, DIM);

  rmsnorm_bf_k<<<MTOT, 256, 0, stream>>>(hb, fnw, xn);

  gemm8p<bf16_t, true, false><<<512, 512, 0, stream>>>(
      xn, w1b, f1, nullptr, MTOT, HIDDEN, DIM);

  // FFN2 + h residual (bf16) -> out fp32
  gemm8p_n128<float, false, true, 3><<<256, 512, 0, stream>>>(
      f1, w2b, out, hb, MTOT, DIM, HIDDEN);
}